// Round 1
// baseline (31339.130 us; speedup 1.0000x reference)
//
#include <hip/hip_runtime.h>
#include <hip/hip_cooperative_groups.h>
#include <math.h>

namespace cg = cooperative_groups;

#define S_LEN 512
#define BATCH 64
#define HSZ   512
#define G4    2048

// ---------------- Kernel 1: x_proj = input @ W_ih^T + (b_ih + b_hh) ----------
// A: (32768, 512) row-major; W: (2048, 512) row-major; C: (32768, 2048)
__global__ __launch_bounds__(256) void xproj_gemm(
    const float* __restrict__ A,
    const float* __restrict__ W,
    const float* __restrict__ bih,
    const float* __restrict__ bhh,
    float* __restrict__ C)
{
  __shared__ float As[16][68];
  __shared__ float Bs[16][68];
  const int tid = threadIdx.x;
  const int bn = blockIdx.x & 31;
  const int bm = blockIdx.x >> 5;
  const int m0 = bm << 6, n0 = bn << 6;
  const int tx = tid & 15, ty = tid >> 4;
  const int lrow = tid >> 2;          // 0..63
  const int lk4 = (tid & 3) << 2;     // 0,4,8,12
  float acc[4][4] = {};
  for (int kb = 0; kb < 512; kb += 16) {
    const float4 a = *(const float4*)(A + (size_t)(m0 + lrow)*512 + kb + lk4);
    const float4 b = *(const float4*)(W + (size_t)(n0 + lrow)*512 + kb + lk4);
    As[lk4+0][lrow]=a.x; As[lk4+1][lrow]=a.y; As[lk4+2][lrow]=a.z; As[lk4+3][lrow]=a.w;
    Bs[lk4+0][lrow]=b.x; Bs[lk4+1][lrow]=b.y; Bs[lk4+2][lrow]=b.z; Bs[lk4+3][lrow]=b.w;
    __syncthreads();
    #pragma unroll
    for (int k = 0; k < 16; ++k) {
      const float4 a4 = *(const float4*)(&As[k][ty<<2]);
      const float4 b4 = *(const float4*)(&Bs[k][tx<<2]);
      acc[0][0] += a4.x*b4.x; acc[0][1] += a4.x*b4.y; acc[0][2] += a4.x*b4.z; acc[0][3] += a4.x*b4.w;
      acc[1][0] += a4.y*b4.x; acc[1][1] += a4.y*b4.y; acc[1][2] += a4.y*b4.z; acc[1][3] += a4.y*b4.w;
      acc[2][0] += a4.z*b4.x; acc[2][1] += a4.z*b4.y; acc[2][2] += a4.z*b4.z; acc[2][3] += a4.z*b4.w;
      acc[3][0] += a4.w*b4.x; acc[3][1] += a4.w*b4.y; acc[3][2] += a4.w*b4.z; acc[3][3] += a4.w*b4.w;
    }
    __syncthreads();
  }
  const int n = n0 + (tx<<2);
  const float4 bias = { bih[n]+bhh[n], bih[n+1]+bhh[n+1],
                        bih[n+2]+bhh[n+2], bih[n+3]+bhh[n+3] };
  for (int i = 0; i < 4; ++i) {
    const int m = m0 + (ty<<2) + i;
    float4 o = { acc[i][0]+bias.x, acc[i][1]+bias.y, acc[i][2]+bias.z, acc[i][3]+bias.w };
    *(float4*)(C + (size_t)m*2048 + n) = o;
  }
}

// ---------------- Kernel 2: persistent cooperative recurrence ----------------
// 256 blocks x 256 threads, 1 block/CU. Block owns (8 batches) x (16 j).
// LDS: W rows (4 gates x 16 j) stride-516, h tile stride-516, gate buf, c state.
#define BT 8
#define JT 16
#define RSTRIDE 516
#define REC_LDS_BYTES ((64*RSTRIDE + BT*RSTRIDE + 4*JT*BT + JT*BT) * 4)

__device__ __forceinline__ float sigmoidf_(float x) { return 1.0f / (1.0f + __expf(-x)); }

__global__ __launch_bounds__(256, 1) void lstm_rec(
    const float* __restrict__ xproj,  // (S, B, 2048)
    const float* __restrict__ whh,    // (2048, 512)
    const float* __restrict__ h0,     // (B, 512)
    const float* __restrict__ c0,     // (B, 512)
    float* __restrict__ out)          // (S,B,512) then h_T then c_T
{
  extern __shared__ float lds[];
  float* Ws = lds;                     // 64 * 516
  float* hs = lds + 64*RSTRIDE;        // 8 * 516
  float* gb = hs + BT*RSTRIDE;         // 512  (gate, jl, bl)
  float* cs = gb + 4*JT*BT;            // 128  (jl, bl)

  const int tid = threadIdx.x;
  const int bt = blockIdx.x & 7;       // 8 b-tiles
  const int jt = blockIdx.x >> 3;      // 32 j-tiles
  const int b0 = bt << 3;
  const int j0 = jt << 4;

  // Load this block's 64 W_hh rows into LDS (row g = gate*512 + j0 + jl)
  for (int idx = tid; idx < 8192; idx += 256) {
    const int f = idx << 2;            // flat float idx in 64x512
    const int r = f >> 9;              // local row 0..63
    const int k = f & 511;
    const int gate = r >> 4;
    const int jl = r & 15;
    const float4 w = *(const float4*)(whh + (size_t)((gate<<9) + j0 + jl)*512 + k);
    *(float4*)(Ws + r*RSTRIDE + k) = w;
  }
  if (tid < 128) cs[tid] = c0[(size_t)(b0 + (tid & 7))*512 + j0 + (tid >> 3)];

  // Each thread owns 2 dot products: (gate0, jl, bl) and (gate0+2, jl, bl)
  const int gate0 = tid >> 7;          // 0 or 1
  const int rem = tid & 127;
  const int jl = rem >> 3;             // 0..15
  const int bl = rem & 7;              // 0..7
  const float* wp0 = Ws + ((gate0<<4) + jl) * RSTRIDE;
  const float* wp1 = Ws + (((gate0+2)<<4) + jl) * RSTRIDE;
  const float* hrow = hs + bl * RSTRIDE;
  const int grow0 = (gate0<<9) + j0 + jl;
  const int grow1 = ((gate0+2)<<9) + j0 + jl;

  cg::grid_group grid = cg::this_grid();

  for (int t = 0; t < S_LEN; ++t) {
    // Stage h_{t-1} rows b0..b0+7 into LDS
    const float* hsrc = (t == 0) ? h0 : (out + (size_t)(t-1)*BATCH*HSZ);
    for (int idx = tid; idx < 1024; idx += 256) {
      const int r = idx >> 7;
      const int k4 = (idx & 127) << 2;
      const float4 v = *(const float4*)(hsrc + (size_t)(b0 + r)*512 + k4);
      *(float4*)(hs + r*RSTRIDE + k4) = v;
    }
    __syncthreads();

    float acc0 = 0.f, acc1 = 0.f;
    #pragma unroll 4
    for (int kk = 0; kk < 128; ++kk) {
      const int k4 = kk << 2;
      const float4 h4 = *(const float4*)(hrow + k4);
      const float4 wa = *(const float4*)(wp0 + k4);
      const float4 wb = *(const float4*)(wp1 + k4);
      acc0 += h4.x*wa.x + h4.y*wa.y + h4.z*wa.z + h4.w*wa.w;
      acc1 += h4.x*wb.x + h4.y*wb.y + h4.z*wb.z + h4.w*wb.w;
    }
    const size_t xbase = (size_t)t * BATCH * G4 + (size_t)(b0 + bl) * G4;
    acc0 += xproj[xbase + grow0];
    acc1 += xproj[xbase + grow1];
    gb[((gate0<<4) + jl)*8 + bl] = acc0;
    gb[(((gate0+2)<<4) + jl)*8 + bl] = acc1;
    __syncthreads();

    if (tid < 128) {
      const int jjl = tid >> 3, bbl = tid & 7;
      const float ig = sigmoidf_(gb[(0*16+jjl)*8 + bbl]);
      const float fg = sigmoidf_(gb[(1*16+jjl)*8 + bbl]);
      const float gg = tanhf(gb[(2*16+jjl)*8 + bbl]);
      const float og = sigmoidf_(gb[(3*16+jjl)*8 + bbl]);
      const float c = fg * cs[tid] + ig * gg;
      cs[tid] = c;
      const float h = og * tanhf(c);
      out[(size_t)t*BATCH*HSZ + (size_t)(b0+bbl)*512 + j0 + jjl] = h;
      if (t == S_LEN-1) {
        out[(size_t)S_LEN*BATCH*HSZ + (size_t)(b0+bbl)*512 + j0 + jjl] = h;
        out[(size_t)S_LEN*BATCH*HSZ + BATCH*HSZ + (size_t)(b0+bbl)*512 + j0 + jjl] = c;
      }
    }
    __threadfence();
    grid.sync();
  }
}

extern "C" void kernel_launch(void* const* d_in, const int* in_sizes, int n_in,
                              void* d_out, int out_size, void* d_ws, size_t ws_size,
                              hipStream_t stream) {
  (void)in_sizes; (void)n_in; (void)out_size; (void)ws_size;
  const float* input = (const float*)d_in[0];  // (512, 64, 512)
  const float* h0p   = (const float*)d_in[1];  // (64, 512)
  const float* c0p   = (const float*)d_in[2];  // (64, 512)
  const float* wih   = (const float*)d_in[3];  // (1, 2048, 512)
  const float* whhp  = (const float*)d_in[4];  // (1, 2048, 512)
  const float* bih   = (const float*)d_in[5];  // (1, 2048)
  const float* bhh   = (const float*)d_in[6];  // (1, 2048)
  // d_in[7] = direction = 0, leading dims are 1 -> ignore
  float* outp  = (float*)d_out;
  float* xproj = (float*)d_ws;                 // needs 32768*2048*4 = 256 MB

  // Phase 1: big input-projection GEMM
  xproj_gemm<<<dim3(16384), dim3(256), 0, stream>>>(input, wih, bih, bhh, xproj);

  // Phase 2: persistent cooperative recurrence
  hipFuncSetAttribute((const void*)lstm_rec,
                      hipFuncAttributeMaxDynamicSharedMemorySize, REC_LDS_BYTES);
  const float* xp = xproj;
  void* args[] = { (void*)&xp, (void*)&whhp, (void*)&h0p, (void*)&c0p, (void*)&outp };
  hipLaunchCooperativeKernel((const void*)lstm_rec, dim3(256), dim3(256),
                             args, REC_LDS_BYTES, stream);
}

// Round 2
// 11832.394 us; speedup vs baseline: 2.6486x; 2.6486x over previous
//
#include <hip/hip_runtime.h>
#include <math.h>

#define S_LEN 512
#define BATCH 64
#define HSZ   512
#define G4    2048

// ---------------- Kernel 1: x_proj = input @ W_ih^T + (b_ih + b_hh) ----------
// A: (32768, 512) row-major; W: (2048, 512) row-major; C: (32768, 2048)
__global__ __launch_bounds__(256) void xproj_gemm(
    const float* __restrict__ A,
    const float* __restrict__ W,
    const float* __restrict__ bih,
    const float* __restrict__ bhh,
    float* __restrict__ C)
{
  __shared__ float As[16][68];
  __shared__ float Bs[16][68];
  const int tid = threadIdx.x;
  const int bn = blockIdx.x & 31;
  const int bm = blockIdx.x >> 5;
  const int m0 = bm << 6, n0 = bn << 6;
  const int tx = tid & 15, ty = tid >> 4;
  const int lrow = tid >> 2;          // 0..63
  const int lk4 = (tid & 3) << 2;     // 0,4,8,12
  float acc[4][4] = {};
  for (int kb = 0; kb < 512; kb += 16) {
    const float4 a = *(const float4*)(A + (size_t)(m0 + lrow)*512 + kb + lk4);
    const float4 b = *(const float4*)(W + (size_t)(n0 + lrow)*512 + kb + lk4);
    As[lk4+0][lrow]=a.x; As[lk4+1][lrow]=a.y; As[lk4+2][lrow]=a.z; As[lk4+3][lrow]=a.w;
    Bs[lk4+0][lrow]=b.x; Bs[lk4+1][lrow]=b.y; Bs[lk4+2][lrow]=b.z; Bs[lk4+3][lrow]=b.w;
    __syncthreads();
    #pragma unroll
    for (int k = 0; k < 16; ++k) {
      const float4 a4 = *(const float4*)(&As[k][ty<<2]);
      const float4 b4 = *(const float4*)(&Bs[k][tx<<2]);
      acc[0][0] += a4.x*b4.x; acc[0][1] += a4.x*b4.y; acc[0][2] += a4.x*b4.z; acc[0][3] += a4.x*b4.w;
      acc[1][0] += a4.y*b4.x; acc[1][1] += a4.y*b4.y; acc[1][2] += a4.y*b4.z; acc[1][3] += a4.y*b4.w;
      acc[2][0] += a4.z*b4.x; acc[2][1] += a4.z*b4.y; acc[2][2] += a4.z*b4.z; acc[2][3] += a4.z*b4.w;
      acc[3][0] += a4.w*b4.x; acc[3][1] += a4.w*b4.y; acc[3][2] += a4.w*b4.z; acc[3][3] += a4.w*b4.w;
    }
    __syncthreads();
  }
  const int n = n0 + (tx<<2);
  const float4 bias = { bih[n]+bhh[n], bih[n+1]+bhh[n+1],
                        bih[n+2]+bhh[n+2], bih[n+3]+bhh[n+3] };
  for (int i = 0; i < 4; ++i) {
    const int m = m0 + (ty<<2) + i;
    float4 o = { acc[i][0]+bias.x, acc[i][1]+bias.y, acc[i][2]+bias.z, acc[i][3]+bias.w };
    *(float4*)(C + (size_t)m*2048 + n) = o;
  }
}

// ---------------- Kernel 2: persistent recurrence, lean custom barrier -------
// 256 blocks x 256 threads, 1 block/CU. Block owns (8 batches) x (16 j).
// Cross-block h exchange via agent-scope relaxed atomics (sc0 sc1 -> device
// coherence point, bypassing the non-coherent per-XCD L2s). Barrier is a
// monotonic counter + generation flag in __device__ globals: no reset store,
// no cache-maintenance instructions, one vmcnt(0) drain before arrival.
#define BT 8
#define JT 16
#define RSTRIDE 516
#define REC_LDS_BYTES ((64*RSTRIDE + BT*RSTRIDE + 4*JT*BT + JT*BT) * 4)
#define NBLOCKS 256

__device__ unsigned g_cnt = 0;   // monotonic arrival counter (wraps mod 2^32, 256 | 2^32)
__device__ unsigned g_gen = 0;   // generation: bumps once per completed barrier

__device__ __forceinline__ float sigmoidf_(float x) { return 1.0f / (1.0f + __expf(-x)); }

__device__ __forceinline__ float gload(const float* p) {
  return __hip_atomic_load(p, __ATOMIC_RELAXED, __HIP_MEMORY_SCOPE_AGENT);
}
__device__ __forceinline__ void gstore(float* p, float v) {
  __hip_atomic_store(p, v, __ATOMIC_RELAXED, __HIP_MEMORY_SCOPE_AGENT);
}

__device__ __forceinline__ void grid_barrier() {
  __syncthreads();
  if (threadIdx.x == 0) {
    // Drain this block's agent-scope h-stores to the coherence point.
    asm volatile("s_waitcnt vmcnt(0)" ::: "memory");
    const unsigned g = __hip_atomic_load(&g_gen, __ATOMIC_RELAXED, __HIP_MEMORY_SCOPE_AGENT);
    const unsigned a = __hip_atomic_fetch_add(&g_cnt, 1u, __ATOMIC_RELAXED, __HIP_MEMORY_SCOPE_AGENT);
    if ((a & (NBLOCKS - 1u)) == (NBLOCKS - 1u)) {
      __hip_atomic_store(&g_gen, g + 1u, __ATOMIC_RELAXED, __HIP_MEMORY_SCOPE_AGENT);
    } else {
      while (__hip_atomic_load(&g_gen, __ATOMIC_RELAXED, __HIP_MEMORY_SCOPE_AGENT) == g) {
        __builtin_amdgcn_s_sleep(1);
      }
    }
  }
  __syncthreads();
}

__global__ __launch_bounds__(256, 1) void lstm_rec(
    const float* __restrict__ xproj,  // (S, B, 2048)
    const float* __restrict__ whh,    // (2048, 512)
    const float* __restrict__ h0,     // (B, 512)
    const float* __restrict__ c0,     // (B, 512)
    float* __restrict__ out)          // (S,B,512) then h_T then c_T
{
  extern __shared__ float lds[];
  float* Ws = lds;                     // 64 * 516
  float* hs = lds + 64*RSTRIDE;        // 8 * 516
  float* gb = hs + BT*RSTRIDE;         // 512  (gate, jl, bl)
  float* cs = gb + 4*JT*BT;            // 128  (jl, bl)

  const int tid = threadIdx.x;
  const int bt = blockIdx.x & 7;       // 8 b-tiles
  const int jt = blockIdx.x >> 3;      // 32 j-tiles
  const int b0 = bt << 3;
  const int j0 = jt << 4;

  // Load this block's 64 W_hh rows into LDS (row g = gate*512 + j0 + jl)
  for (int idx = tid; idx < 8192; idx += 256) {
    const int f = idx << 2;            // flat float idx in 64x512
    const int r = f >> 9;              // local row 0..63
    const int k = f & 511;
    const int gate = r >> 4;
    const int jl = r & 15;
    const float4 w = *(const float4*)(whh + (size_t)((gate<<9) + j0 + jl)*512 + k);
    *(float4*)(Ws + r*RSTRIDE + k) = w;
  }
  if (tid < 128) cs[tid] = c0[(size_t)(b0 + (tid & 7))*512 + j0 + (tid >> 3)];

  // Each thread owns 2 dot products: (gate0, jl, bl) and (gate0+2, jl, bl)
  const int gate0 = tid >> 7;          // 0 or 1
  const int rem = tid & 127;
  const int jl = rem >> 3;             // 0..15
  const int bl = rem & 7;              // 0..7
  const float* wp0 = Ws + ((gate0<<4) + jl) * RSTRIDE;
  const float* wp1 = Ws + (((gate0+2)<<4) + jl) * RSTRIDE;
  const float* hrow = hs + bl * RSTRIDE;
  const int grow0 = (gate0<<9) + j0 + jl;
  const int grow1 = ((gate0+2)<<9) + j0 + jl;

  for (int t = 0; t < S_LEN; ++t) {
    // Stage h_{t-1} rows b0..b0+7 into LDS via agent-scope (coherent) loads
    const float* hsrc = (t == 0) ? h0 : (out + (size_t)(t-1)*BATCH*HSZ);
    for (int idx = tid; idx < 4096; idx += 256) {
      const int r = idx >> 9;          // 0..7
      const int k = idx & 511;
      hs[r*RSTRIDE + k] = gload(hsrc + (size_t)(b0 + r)*512 + k);
    }
    __syncthreads();

    float acc0 = 0.f, acc1 = 0.f;
    #pragma unroll 4
    for (int kk = 0; kk < 128; ++kk) {
      const int k4 = kk << 2;
      const float4 h4 = *(const float4*)(hrow + k4);
      const float4 wa = *(const float4*)(wp0 + k4);
      const float4 wb = *(const float4*)(wp1 + k4);
      acc0 += h4.x*wa.x + h4.y*wa.y + h4.z*wa.z + h4.w*wa.w;
      acc1 += h4.x*wb.x + h4.y*wb.y + h4.z*wb.z + h4.w*wb.w;
    }
    const size_t xbase = (size_t)t * BATCH * G4 + (size_t)(b0 + bl) * G4;
    acc0 += xproj[xbase + grow0];
    acc1 += xproj[xbase + grow1];
    gb[((gate0<<4) + jl)*8 + bl] = acc0;
    gb[(((gate0+2)<<4) + jl)*8 + bl] = acc1;
    __syncthreads();

    if (tid < 128) {
      const int jjl = tid >> 3, bbl = tid & 7;
      const float ig = sigmoidf_(gb[(0*16+jjl)*8 + bbl]);
      const float fg = sigmoidf_(gb[(1*16+jjl)*8 + bbl]);
      const float gg = tanhf(gb[(2*16+jjl)*8 + bbl]);
      const float og = sigmoidf_(gb[(3*16+jjl)*8 + bbl]);
      const float c = fg * cs[tid] + ig * gg;
      cs[tid] = c;
      const float h = og * tanhf(c);
      // h is both the result and the next step's input: agent-scope store
      gstore(out + (size_t)t*BATCH*HSZ + (size_t)(b0+bbl)*512 + j0 + jjl, h);
      if (t == S_LEN-1) {
        out[(size_t)S_LEN*BATCH*HSZ + (size_t)(b0+bbl)*512 + j0 + jjl] = h;
        out[(size_t)S_LEN*BATCH*HSZ + BATCH*HSZ + (size_t)(b0+bbl)*512 + j0 + jjl] = c;
      }
    }
    if (t < S_LEN - 1) grid_barrier();
  }
}

extern "C" void kernel_launch(void* const* d_in, const int* in_sizes, int n_in,
                              void* d_out, int out_size, void* d_ws, size_t ws_size,
                              hipStream_t stream) {
  (void)in_sizes; (void)n_in; (void)out_size; (void)ws_size;
  const float* input = (const float*)d_in[0];  // (512, 64, 512)
  const float* h0p   = (const float*)d_in[1];  // (64, 512)
  const float* c0p   = (const float*)d_in[2];  // (64, 512)
  const float* wih   = (const float*)d_in[3];  // (1, 2048, 512)
  const float* whhp  = (const float*)d_in[4];  // (1, 2048, 512)
  const float* bih   = (const float*)d_in[5];  // (1, 2048)
  const float* bhh   = (const float*)d_in[6];  // (1, 2048)
  float* outp  = (float*)d_out;
  float* xproj = (float*)d_ws;                 // 32768*2048*4 = 256 MB

  // Phase 1: big input-projection GEMM
  xproj_gemm<<<dim3(16384), dim3(256), 0, stream>>>(input, wih, bih, bhh, xproj);

  // Phase 2: persistent recurrence (cooperative launch for co-residency only;
  // sync is the hand-rolled agent-scope barrier inside)
  hipFuncSetAttribute((const void*)lstm_rec,
                      hipFuncAttributeMaxDynamicSharedMemorySize, REC_LDS_BYTES);
  const float* xp = xproj;
  void* args[] = { (void*)&xp, (void*)&whhp, (void*)&h0p, (void*)&c0p, (void*)&outp };
  hipLaunchCooperativeKernel((const void*)lstm_rec, dim3(256), dim3(256),
                             args, REC_LDS_BYTES, stream);
}

// Round 3
// 6383.562 us; speedup vs baseline: 4.9093x; 1.8536x over previous
//
#include <hip/hip_runtime.h>
#include <math.h>

#define S_LEN 512
#define BATCH 64
#define HSZ   512
#define G4    2048

// ---------------- Kernel 1: x_proj = input @ W_ih^T + (b_ih + b_hh) ----------
// A: (32768, 512) row-major; W: (2048, 512) row-major; C: (32768, 2048)
__global__ __launch_bounds__(256) void xproj_gemm(
    const float* __restrict__ A,
    const float* __restrict__ W,
    const float* __restrict__ bih,
    const float* __restrict__ bhh,
    float* __restrict__ C)
{
  __shared__ float As[16][68];
  __shared__ float Bs[16][68];
  const int tid = threadIdx.x;
  const int bn = blockIdx.x & 31;
  const int bm = blockIdx.x >> 5;
  const int m0 = bm << 6, n0 = bn << 6;
  const int tx = tid & 15, ty = tid >> 4;
  const int lrow = tid >> 2;          // 0..63
  const int lk4 = (tid & 3) << 2;     // 0,4,8,12
  float acc[4][4] = {};
  for (int kb = 0; kb < 512; kb += 16) {
    const float4 a = *(const float4*)(A + (size_t)(m0 + lrow)*512 + kb + lk4);
    const float4 b = *(const float4*)(W + (size_t)(n0 + lrow)*512 + kb + lk4);
    As[lk4+0][lrow]=a.x; As[lk4+1][lrow]=a.y; As[lk4+2][lrow]=a.z; As[lk4+3][lrow]=a.w;
    Bs[lk4+0][lrow]=b.x; Bs[lk4+1][lrow]=b.y; Bs[lk4+2][lrow]=b.z; Bs[lk4+3][lrow]=b.w;
    __syncthreads();
    #pragma unroll
    for (int k = 0; k < 16; ++k) {
      const float4 a4 = *(const float4*)(&As[k][ty<<2]);
      const float4 b4 = *(const float4*)(&Bs[k][tx<<2]);
      acc[0][0] += a4.x*b4.x; acc[0][1] += a4.x*b4.y; acc[0][2] += a4.x*b4.z; acc[0][3] += a4.x*b4.w;
      acc[1][0] += a4.y*b4.x; acc[1][1] += a4.y*b4.y; acc[1][2] += a4.y*b4.z; acc[1][3] += a4.y*b4.w;
      acc[2][0] += a4.z*b4.x; acc[2][1] += a4.z*b4.y; acc[2][2] += a4.z*b4.z; acc[2][3] += a4.z*b4.w;
      acc[3][0] += a4.w*b4.x; acc[3][1] += a4.w*b4.y; acc[3][2] += a4.w*b4.z; acc[3][3] += a4.w*b4.w;
    }
    __syncthreads();
  }
  const int n = n0 + (tx<<2);
  const float4 bias = { bih[n]+bhh[n], bih[n+1]+bhh[n+1],
                        bih[n+2]+bhh[n+2], bih[n+3]+bhh[n+3] };
  for (int i = 0; i < 4; ++i) {
    const int m = m0 + (ty<<2) + i;
    float4 o = { acc[i][0]+bias.x, acc[i][1]+bias.y, acc[i][2]+bias.z, acc[i][3]+bias.w };
    *(float4*)(C + (size_t)m*2048 + n) = o;
  }
}

// ---------------- Kernel 2: persistent recurrence, distributed flag sync -----
// 256 blocks = 8 independent groups (by batch-tile bt) x 32 producers (jt).
// Block (bt,jt) consumes h only for batches b0..b0+7, produced by blocks
// (bt,*) -> sync is GROUP-LOCAL: per-producer monotonic flags, no atomics RMW,
// no reset (own-flag-base trick survives graph replays).
#define BT 8
#define JT 16
#define RSTRIDE 516
#define REC_LDS_BYTES ((64*RSTRIDE + BT*RSTRIDE + 4*JT*BT + JT*BT) * 4)

__device__ unsigned g_flags[8][32];   // zero-init; grows by 511 per launch

__device__ __forceinline__ float sigmoidf_(float x) { return 1.0f / (1.0f + __expf(-x)); }

__device__ __forceinline__ float gload(const float* p) {
  return __hip_atomic_load(p, __ATOMIC_RELAXED, __HIP_MEMORY_SCOPE_AGENT);
}
__device__ __forceinline__ void gstore(float* p, float v) {
  __hip_atomic_store(p, v, __ATOMIC_RELAXED, __HIP_MEMORY_SCOPE_AGENT);
}
// Coherent (cache-bypassing) 4x float4 load + single drain: h-exchange staging.
__device__ __forceinline__ void gload4x4(const float* p0, const float* p1,
                                         const float* p2, const float* p3,
                                         float4& v0, float4& v1,
                                         float4& v2, float4& v3) {
  asm volatile(
      "global_load_dwordx4 %0, %4, off sc0 sc1\n\t"
      "global_load_dwordx4 %1, %5, off sc0 sc1\n\t"
      "global_load_dwordx4 %2, %6, off sc0 sc1\n\t"
      "global_load_dwordx4 %3, %7, off sc0 sc1\n\t"
      "s_waitcnt vmcnt(0)"
      : "=&v"(v0), "=&v"(v1), "=&v"(v2), "=&v"(v3)
      : "v"(p0), "v"(p1), "v"(p2), "v"(p3)
      : "memory");
}

__global__ __launch_bounds__(256, 1) void lstm_rec(
    const float* __restrict__ xproj,  // (S, B, 2048)
    const float* __restrict__ whh,    // (2048, 512)
    const float* __restrict__ h0,     // (B, 512)
    const float* __restrict__ c0,     // (B, 512)
    float* __restrict__ out)          // (S,B,512) then h_T then c_T
{
  extern __shared__ float lds[];
  float* Ws = lds;                     // 64 * 516
  float* hs = lds + 64*RSTRIDE;        // 8 * 516
  float* gb = hs + BT*RSTRIDE;         // 512  (gate, jl, bl)
  float* cs = gb + 4*JT*BT;            // 128  (jl, bl)

  const int tid = threadIdx.x;
  const int bt = blockIdx.x & 7;       // 8 groups (batch tiles)
  const int jt = blockIdx.x >> 3;      // 32 producers per group
  const int b0 = bt << 3;
  const int j0 = jt << 4;

  // Monotonic flag base: all flags in a group are equal at launch start.
  const unsigned base = __hip_atomic_load(&g_flags[bt][jt], __ATOMIC_RELAXED,
                                          __HIP_MEMORY_SCOPE_AGENT);

  // Load this block's 64 W_hh rows into LDS (row g = gate*512 + j0 + jl)
  for (int idx = tid; idx < 8192; idx += 256) {
    const int f = idx << 2;            // flat float idx in 64x512
    const int r = f >> 9;              // local row 0..63
    const int k = f & 511;
    const int gate = r >> 4;
    const int jl = r & 15;
    const float4 w = *(const float4*)(whh + (size_t)((gate<<9) + j0 + jl)*512 + k);
    *(float4*)(Ws + r*RSTRIDE + k) = w;
  }
  if (tid < 128) cs[tid] = c0[(size_t)(b0 + (tid & 7))*512 + j0 + (tid >> 3)];

  // Each thread owns 2 dot products: (gate0, jl, bl) and (gate0+2, jl, bl)
  const int gate0 = tid >> 7;          // 0 or 1
  const int rem = tid & 127;
  const int jl = rem >> 3;             // 0..15
  const int bl = rem & 7;              // 0..7
  const float* wp0 = Ws + ((gate0<<4) + jl) * RSTRIDE;
  const float* wp1 = Ws + (((gate0+2)<<4) + jl) * RSTRIDE;
  const float* hrow = hs + bl * RSTRIDE;
  const int grow0 = (gate0<<9) + j0 + jl;
  const int grow1 = ((gate0+2)<<9) + j0 + jl;

  // Staging geometry: 4 float4 / thread, rows {rbase, rbase+2, +4, +6}
  const int rbase = tid >> 7;          // 0 or 1
  const int kk4 = (tid & 127) << 2;    // 0..508
  const int flag_lane = tid & 31;

  for (int t = 0; t < S_LEN; ++t) {
    // xproj prefetch (independent of h) — issue before the flag wait
    const size_t xbase = (size_t)t * BATCH * G4 + (size_t)(b0 + bl) * G4;
    const float xp0 = xproj[xbase + grow0];
    const float xp1 = xproj[xbase + grow1];

    if (t > 0) {
      const unsigned target = base + (unsigned)t;
      for (;;) {
        const unsigned f = __hip_atomic_load(&g_flags[bt][flag_lane],
                                             __ATOMIC_RELAXED, __HIP_MEMORY_SCOPE_AGENT);
        const int ok = (flag_lane == jt) | ((int)(f - target) >= 0);
        if (__all(ok)) break;
        __builtin_amdgcn_s_sleep(1);
      }
    }

    // Stage h_{t-1} rows b0..b0+7 into LDS (coherent x4 loads)
    const float* hsrc = (t == 0) ? h0 : (out + (size_t)(t-1)*BATCH*HSZ);
    {
      float4 v0, v1, v2, v3;
      gload4x4(hsrc + (size_t)(b0 + rbase + 0)*512 + kk4,
               hsrc + (size_t)(b0 + rbase + 2)*512 + kk4,
               hsrc + (size_t)(b0 + rbase + 4)*512 + kk4,
               hsrc + (size_t)(b0 + rbase + 6)*512 + kk4,
               v0, v1, v2, v3);
      *(float4*)(hs + (rbase + 0)*RSTRIDE + kk4) = v0;
      *(float4*)(hs + (rbase + 2)*RSTRIDE + kk4) = v1;
      *(float4*)(hs + (rbase + 4)*RSTRIDE + kk4) = v2;
      *(float4*)(hs + (rbase + 6)*RSTRIDE + kk4) = v3;
    }
    __syncthreads();

    float acc0 = xp0, acc1 = xp1;
    #pragma unroll 4
    for (int kk = 0; kk < 128; ++kk) {
      const int k4 = kk << 2;
      const float4 h4 = *(const float4*)(hrow + k4);
      const float4 wa = *(const float4*)(wp0 + k4);
      const float4 wb = *(const float4*)(wp1 + k4);
      acc0 += h4.x*wa.x + h4.y*wa.y + h4.z*wa.z + h4.w*wa.w;
      acc1 += h4.x*wb.x + h4.y*wb.y + h4.z*wb.z + h4.w*wb.w;
    }
    gb[((gate0<<4) + jl)*8 + bl] = acc0;
    gb[(((gate0+2)<<4) + jl)*8 + bl] = acc1;
    __syncthreads();

    if (tid < 128) {
      const int jjl = tid >> 3, bbl = tid & 7;
      const float ig = sigmoidf_(gb[(0*16+jjl)*8 + bbl]);
      const float fg = sigmoidf_(gb[(1*16+jjl)*8 + bbl]);
      const float gg = tanhf(gb[(2*16+jjl)*8 + bbl]);
      const float og = sigmoidf_(gb[(3*16+jjl)*8 + bbl]);
      const float c = fg * cs[tid] + ig * gg;
      cs[tid] = c;
      const float h = og * tanhf(c);
      // h is both the result and the next step's input: agent-scope store
      gstore(out + (size_t)t*BATCH*HSZ + (size_t)(b0+bbl)*512 + j0 + jjl, h);
      if (t == S_LEN-1) {
        out[(size_t)S_LEN*BATCH*HSZ + (size_t)(b0+bbl)*512 + j0 + jjl] = h;
        out[(size_t)S_LEN*BATCH*HSZ + BATCH*HSZ + (size_t)(b0+bbl)*512 + j0 + jjl] = c;
      }
    }
    if (t < S_LEN - 1) {
      // Drain every wave's h-stores, then publish this producer's flag.
      asm volatile("s_waitcnt vmcnt(0)" ::: "memory");
      __syncthreads();
      if (tid == 0) {
        __hip_atomic_store(&g_flags[bt][jt], base + (unsigned)t + 1u,
                           __ATOMIC_RELAXED, __HIP_MEMORY_SCOPE_AGENT);
      }
    }
  }
}

extern "C" void kernel_launch(void* const* d_in, const int* in_sizes, int n_in,
                              void* d_out, int out_size, void* d_ws, size_t ws_size,
                              hipStream_t stream) {
  (void)in_sizes; (void)n_in; (void)out_size; (void)ws_size;
  const float* input = (const float*)d_in[0];  // (512, 64, 512)
  const float* h0p   = (const float*)d_in[1];  // (64, 512)
  const float* c0p   = (const float*)d_in[2];  // (64, 512)
  const float* wih   = (const float*)d_in[3];  // (1, 2048, 512)
  const float* whhp  = (const float*)d_in[4];  // (1, 2048, 512)
  const float* bih   = (const float*)d_in[5];  // (1, 2048)
  const float* bhh   = (const float*)d_in[6];  // (1, 2048)
  float* outp  = (float*)d_out;
  float* xproj = (float*)d_ws;                 // 32768*2048*4 = 256 MB

  // Phase 1: big input-projection GEMM
  xproj_gemm<<<dim3(16384), dim3(256), 0, stream>>>(input, wih, bih, bhh, xproj);

  // Phase 2: persistent recurrence (cooperative launch for co-residency only;
  // sync is the distributed per-group flag protocol inside)
  hipFuncSetAttribute((const void*)lstm_rec,
                      hipFuncAttributeMaxDynamicSharedMemorySize, REC_LDS_BYTES);
  const float* xp = xproj;
  void* args[] = { (void*)&xp, (void*)&whhp, (void*)&h0p, (void*)&c0p, (void*)&outp };
  hipLaunchCooperativeKernel((const void*)lstm_rec, dim3(256), dim3(256),
                             args, REC_LDS_BYTES, stream);
}

// Round 5
// 3107.356 us; speedup vs baseline: 10.0855x; 2.0543x over previous
//
#include <hip/hip_runtime.h>
#include <math.h>

#define S_LEN 512
#define BATCH 64
#define HSZ   512
#define G4    2048

typedef __attribute__((ext_vector_type(8))) short short8;
typedef __attribute__((ext_vector_type(4))) float f32x4;
typedef __attribute__((ext_vector_type(4))) unsigned u32x4;

// ---------------- Kernel 1: x_proj = input @ W_ih^T + (b_ih + b_hh) ----------
// (unchanged from R3 — fp32-exact, ~450 us)
__global__ __launch_bounds__(256) void xproj_gemm(
    const float* __restrict__ A,
    const float* __restrict__ W,
    const float* __restrict__ bih,
    const float* __restrict__ bhh,
    float* __restrict__ C)
{
  __shared__ float As[16][68];
  __shared__ float Bs[16][68];
  const int tid = threadIdx.x;
  const int bn = blockIdx.x & 31;
  const int bm = blockIdx.x >> 5;
  const int m0 = bm << 6, n0 = bn << 6;
  const int tx = tid & 15, ty = tid >> 4;
  const int lrow = tid >> 2;
  const int lk4 = (tid & 3) << 2;
  float acc[4][4] = {};
  for (int kb = 0; kb < 512; kb += 16) {
    const float4 a = *(const float4*)(A + (size_t)(m0 + lrow)*512 + kb + lk4);
    const float4 b = *(const float4*)(W + (size_t)(n0 + lrow)*512 + kb + lk4);
    As[lk4+0][lrow]=a.x; As[lk4+1][lrow]=a.y; As[lk4+2][lrow]=a.z; As[lk4+3][lrow]=a.w;
    Bs[lk4+0][lrow]=b.x; Bs[lk4+1][lrow]=b.y; Bs[lk4+2][lrow]=b.z; Bs[lk4+3][lrow]=b.w;
    __syncthreads();
    #pragma unroll
    for (int k = 0; k < 16; ++k) {
      const float4 a4 = *(const float4*)(&As[k][ty<<2]);
      const float4 b4 = *(const float4*)(&Bs[k][tx<<2]);
      acc[0][0] += a4.x*b4.x; acc[0][1] += a4.x*b4.y; acc[0][2] += a4.x*b4.z; acc[0][3] += a4.x*b4.w;
      acc[1][0] += a4.y*b4.x; acc[1][1] += a4.y*b4.y; acc[1][2] += a4.y*b4.z; acc[1][3] += a4.y*b4.w;
      acc[2][0] += a4.z*b4.x; acc[2][1] += a4.z*b4.y; acc[2][2] += a4.z*b4.z; acc[2][3] += a4.z*b4.w;
      acc[3][0] += a4.w*b4.x; acc[3][1] += a4.w*b4.y; acc[3][2] += a4.w*b4.z; acc[3][3] += a4.w*b4.w;
    }
    __syncthreads();
  }
  const int n = n0 + (tx<<2);
  const float4 bias = { bih[n]+bhh[n], bih[n+1]+bhh[n+1],
                        bih[n+2]+bhh[n+2], bih[n+3]+bhh[n+3] };
  for (int i = 0; i < 4; ++i) {
    const int m = m0 + (ty<<2) + i;
    float4 o = { acc[i][0]+bias.x, acc[i][1]+bias.y, acc[i][2]+bias.z, acc[i][3]+bias.w };
    *(float4*)(C + (size_t)m*2048 + n) = o;
  }
}

// ---------------- Static device exchange state ------------------------------
// h exchanged as bf16 hi/lo planes (hi+lo ~= fp23 precision), double-buffered.
__device__ unsigned short g_hhi[2][BATCH][HSZ];
__device__ unsigned short g_hlo[2][BATCH][HSZ];
__device__ unsigned short g_wbf[G4 * HSZ];   // W_hh as bf16 bits
__device__ unsigned g_flags2[4][16];         // monotonic, never reset

__device__ __forceinline__ unsigned short f2bf(float f) {  // RNE fp32->bf16
  unsigned u = __builtin_bit_cast(unsigned, f);
  u += 0x7fffu + ((u >> 16) & 1u);
  return (unsigned short)(u >> 16);
}
__device__ __forceinline__ float bf2f(unsigned short s) {
  return __builtin_bit_cast(float, (unsigned)s << 16);
}
__device__ __forceinline__ float sigmoidf_(float x) { return 1.0f / (1.0f + __expf(-x)); }

// ---------------- Kernel 1b: convert W_hh fp32 -> bf16 ----------------------
__global__ __launch_bounds__(256) void wcvt(const float* __restrict__ w) {
  const int i = (blockIdx.x * 256 + threadIdx.x) * 4;
  const float4 v = *(const float4*)(w + i);
  ushort4 o;
  o.x = f2bf(v.x); o.y = f2bf(v.y); o.z = f2bf(v.z); o.w = f2bf(v.w);
  *(ushort4*)(g_wbf + i) = o;
}

// ---------------- Kernel 2: persistent MFMA recurrence ----------------------
// 64 blocks = 4 batch-groups (16 b) x 16 j-tiles (32 j). Wave g = gate g,
// 2 MFMA N-subtiles of 16. W_hh bf16 B-frags live in VGPRs (128/lane).
// A = h hi/lo bf16 from exchange planes -> 2 MFMAs per tile per K-step.
#define PSTR 520  // LDS plane row stride (shorts): 1040 B rows, 16B-aligned

__global__ __launch_bounds__(256, 1) void lstm_rec(
    const float* __restrict__ xproj,  // (S, B, 2048)
    const float* __restrict__ h0,     // (B, 512) fp32
    const float* __restrict__ c0,     // (B, 512) fp32
    float* __restrict__ out)          // (S,B,512) then h_T then c_T
{
  __shared__ unsigned short his[16 * PSTR];
  __shared__ unsigned short los[16 * PSTR];
  __shared__ float gbuf[4 * 16 * 33];   // [gate][b][j] stride 33

  const int tid  = threadIdx.x;
  const int bg   = blockIdx.x & 3;      // batch group (16 batches)
  const int jt   = blockIdx.x >> 2;     // 0..15 j-tile
  const int b0   = bg << 4;
  const int j0   = jt << 5;             // 0..480
  const int lane = tid & 63;
  const int g    = tid >> 6;            // wave id == gate id
  const int m    = lane & 15;
  const int quad = lane >> 4;

  const unsigned base = __hip_atomic_load(&g_flags2[bg][jt], __ATOMIC_RELAXED,
                                          __HIP_MEMORY_SCOPE_AGENT);

  // Preload B-frags: wave g, subtile nt, K-step kk; B[n=lane&15][k=quad*8+j]
  short8 Bf[2][16];
  #pragma unroll
  for (int nt = 0; nt < 2; ++nt) {
    #pragma unroll
    for (int kk = 0; kk < 16; ++kk) {
      const int row = (g << 9) + j0 + (nt << 4) + m;   // W_hh row (gate*512 + j) <= 2047
      Bf[nt][kk] = *(const short8*)(g_wbf + row * 512 + kk * 32 + quad * 8);
    }
  }

  // Epilogue ownership: thread -> (batch eb, j-pair ej, ej+1); c in registers
  const int eb = tid >> 4;
  const int ej = (tid & 15) << 1;
  float creg0 = c0[(size_t)(b0 + eb) * 512 + j0 + ej];
  float creg1 = c0[(size_t)(b0 + eb) * 512 + j0 + ej + 1];

  // Staging ownership: thread -> (row sr, 32-short chunk sc)
  const int sr = tid >> 4;
  const int sc = tid & 15;
  const int fl = lane & 15;             // flag index polled by this lane

  for (int t = 0; t < S_LEN; ++t) {
    // xproj prefetch (independent of h): 4 gates x float2
    const float* xpp = xproj + ((size_t)t * BATCH + b0 + eb) * G4 + j0 + ej;
    const float2 xpi = *(const float2*)(xpp);
    const float2 xpf = *(const float2*)(xpp + 512);
    const float2 xpg = *(const float2*)(xpp + 1024);
    const float2 xpo = *(const float2*)(xpp + 1536);

    if (t > 0) {
      // Wait for all 16 producers of this batch group to finish step t-1
      const unsigned target = base + (unsigned)t;
      for (;;) {
        const unsigned f = __hip_atomic_load(&g_flags2[bg][fl], __ATOMIC_RELAXED,
                                             __HIP_MEMORY_SCOPE_AGENT);
        if (__all((int)(f - target) >= 0)) break;
        __builtin_amdgcn_s_sleep(1);
      }
      // Stage hi/lo planes of h_{t-1} (coherent; loads+drain in ONE asm block)
      const unsigned short* hp = &g_hhi[(t - 1) & 1][b0 + sr][sc * 32];
      const unsigned short* lp = &g_hlo[(t - 1) & 1][b0 + sr][sc * 32];
      u32x4 h0v, h1v, h2v, h3v, l0v, l1v, l2v, l3v;
      asm volatile(
          "global_load_dwordx4 %0, %8, off sc0 sc1\n\t"
          "global_load_dwordx4 %1, %9, off sc0 sc1\n\t"
          "global_load_dwordx4 %2, %10, off sc0 sc1\n\t"
          "global_load_dwordx4 %3, %11, off sc0 sc1\n\t"
          "global_load_dwordx4 %4, %12, off sc0 sc1\n\t"
          "global_load_dwordx4 %5, %13, off sc0 sc1\n\t"
          "global_load_dwordx4 %6, %14, off sc0 sc1\n\t"
          "global_load_dwordx4 %7, %15, off sc0 sc1\n\t"
          "s_waitcnt vmcnt(0)"
          : "=&v"(h0v), "=&v"(h1v), "=&v"(h2v), "=&v"(h3v),
            "=&v"(l0v), "=&v"(l1v), "=&v"(l2v), "=&v"(l3v)
          : "v"(hp), "v"(hp + 8), "v"(hp + 16), "v"(hp + 24),
            "v"(lp), "v"(lp + 8), "v"(lp + 16), "v"(lp + 24)
          : "memory");
      unsigned short* hb = his + sr * PSTR + sc * 32;
      unsigned short* lb = los + sr * PSTR + sc * 32;
      *(u32x4*)(hb)      = h0v; *(u32x4*)(hb + 8)  = h1v;
      *(u32x4*)(hb + 16) = h2v; *(u32x4*)(hb + 24) = h3v;
      *(u32x4*)(lb)      = l0v; *(u32x4*)(lb + 8)  = l1v;
      *(u32x4*)(lb + 16) = l2v; *(u32x4*)(lb + 24) = l3v;
    } else {
      // t==0: split h0 fp32 -> hi/lo planes in LDS
      const float* hp0 = h0 + (size_t)(b0 + sr) * 512 + sc * 32;
      unsigned short* hb = his + sr * PSTR + sc * 32;
      unsigned short* lb = los + sr * PSTR + sc * 32;
      #pragma unroll
      for (int i = 0; i < 8; ++i) {
        const float4 v = *(const float4*)(hp0 + i * 4);
        ushort4 h4, l4;
        h4.x = f2bf(v.x); l4.x = f2bf(v.x - bf2f(h4.x));
        h4.y = f2bf(v.y); l4.y = f2bf(v.y - bf2f(h4.y));
        h4.z = f2bf(v.z); l4.z = f2bf(v.z - bf2f(h4.z));
        h4.w = f2bf(v.w); l4.w = f2bf(v.w - bf2f(h4.w));
        *(ushort4*)(hb + i * 4) = h4;
        *(ushort4*)(lb + i * 4) = l4;
      }
    }
    __syncthreads();

    // MFMA: acc[nt] over K=512 (16 steps), A = hi + lo
    f32x4 acc0 = {0.f, 0.f, 0.f, 0.f};
    f32x4 acc1 = {0.f, 0.f, 0.f, 0.f};
    const unsigned short* ab = his + m * PSTR + quad * 8;
    const unsigned short* lb2 = los + m * PSTR + quad * 8;
    #pragma unroll
    for (int kk = 0; kk < 16; ++kk) {
      const short8 ah = *(const short8*)(ab + kk * 32);
      const short8 al = *(const short8*)(lb2 + kk * 32);
      acc0 = __builtin_amdgcn_mfma_f32_16x16x32_bf16(ah, Bf[0][kk], acc0, 0, 0, 0);
      acc1 = __builtin_amdgcn_mfma_f32_16x16x32_bf16(ah, Bf[1][kk], acc1, 0, 0, 0);
      acc0 = __builtin_amdgcn_mfma_f32_16x16x32_bf16(al, Bf[0][kk], acc0, 0, 0, 0);
      acc1 = __builtin_amdgcn_mfma_f32_16x16x32_bf16(al, Bf[1][kk], acc1, 0, 0, 0);
    }
    // C layout: col = lane&15 (j), row = quad*4+i (batch)
    #pragma unroll
    for (int i = 0; i < 4; ++i) {
      gbuf[g * 528 + (quad * 4 + i) * 33 + m]      = acc0[i];
      gbuf[g * 528 + (quad * 4 + i) * 33 + 16 + m] = acc1[i];
    }
    __syncthreads();

    // Epilogue: 2 cells per thread
    const float gi0 = gbuf[0 * 528 + eb * 33 + ej]     + xpi.x;
    const float gi1 = gbuf[0 * 528 + eb * 33 + ej + 1] + xpi.y;
    const float gf0 = gbuf[1 * 528 + eb * 33 + ej]     + xpf.x;
    const float gf1 = gbuf[1 * 528 + eb * 33 + ej + 1] + xpf.y;
    const float gg0 = gbuf[2 * 528 + eb * 33 + ej]     + xpg.x;
    const float gg1 = gbuf[2 * 528 + eb * 33 + ej + 1] + xpg.y;
    const float go0 = gbuf[3 * 528 + eb * 33 + ej]     + xpo.x;
    const float go1 = gbuf[3 * 528 + eb * 33 + ej + 1] + xpo.y;

    creg0 = sigmoidf_(gf0) * creg0 + sigmoidf_(gi0) * tanhf(gg0);
    creg1 = sigmoidf_(gf1) * creg1 + sigmoidf_(gi1) * tanhf(gg1);
    const float h0n = sigmoidf_(go0) * tanhf(creg0);
    const float h1n = sigmoidf_(go1) * tanhf(creg1);

    float2 hv; hv.x = h0n; hv.y = h1n;
    *(float2*)(out + ((size_t)t * BATCH + b0 + eb) * HSZ + j0 + ej) = hv;

    if (t < S_LEN - 1) {
      // Publish hi/lo planes for step t (coherent stores), then flag
      const unsigned short hh0 = f2bf(h0n), hh1 = f2bf(h1n);
      const unsigned short ll0 = f2bf(h0n - bf2f(hh0)), ll1 = f2bf(h1n - bf2f(hh1));
      const unsigned hpack = (unsigned)hh0 | ((unsigned)hh1 << 16);
      const unsigned lpack = (unsigned)ll0 | ((unsigned)ll1 << 16);
      unsigned* hd = (unsigned*)&g_hhi[t & 1][b0 + eb][j0 + ej];
      unsigned* ld = (unsigned*)&g_hlo[t & 1][b0 + eb][j0 + ej];
      asm volatile(
          "global_store_dword %0, %2, off sc0 sc1\n\t"
          "global_store_dword %1, %3, off sc0 sc1"
          :: "v"(hd), "v"(ld), "v"(hpack), "v"(lpack)
          : "memory");
      asm volatile("s_waitcnt vmcnt(0)" ::: "memory");  // every wave drains own stores
      __syncthreads();
      if (tid == 0) {
        __hip_atomic_store(&g_flags2[bg][jt], base + (unsigned)t + 1u,
                           __ATOMIC_RELAXED, __HIP_MEMORY_SCOPE_AGENT);
      }
    } else {
      // h_T, c_T
      *(float2*)(out + (size_t)S_LEN * BATCH * HSZ + (size_t)(b0 + eb) * HSZ + j0 + ej) = hv;
      float2 cv; cv.x = creg0; cv.y = creg1;
      *(float2*)(out + (size_t)S_LEN * BATCH * HSZ + BATCH * HSZ
                 + (size_t)(b0 + eb) * HSZ + j0 + ej) = cv;
    }
  }
}

extern "C" void kernel_launch(void* const* d_in, const int* in_sizes, int n_in,
                              void* d_out, int out_size, void* d_ws, size_t ws_size,
                              hipStream_t stream) {
  (void)in_sizes; (void)n_in; (void)out_size; (void)ws_size;
  const float* input = (const float*)d_in[0];  // (512, 64, 512)
  const float* h0p   = (const float*)d_in[1];  // (64, 512)
  const float* c0p   = (const float*)d_in[2];  // (64, 512)
  const float* wih   = (const float*)d_in[3];  // (1, 2048, 512)
  const float* whhp  = (const float*)d_in[4];  // (1, 2048, 512)
  const float* bih   = (const float*)d_in[5];  // (1, 2048)
  const float* bhh   = (const float*)d_in[6];  // (1, 2048)
  float* outp  = (float*)d_out;
  float* xproj = (float*)d_ws;                 // 256 MB

  xproj_gemm<<<dim3(16384), dim3(256), 0, stream>>>(input, wih, bih, bhh, xproj);
  wcvt<<<dim3(1024), dim3(256), 0, stream>>>(whhp);

  const float* xp = xproj;
  void* args[] = { (void*)&xp, (void*)&h0p, (void*)&c0p, (void*)&outp };
  hipLaunchCooperativeKernel((const void*)lstm_rec, dim3(64), dim3(256),
                             args, 0, stream);
}

// Round 6
// 2147.716 us; speedup vs baseline: 14.5918x; 1.4468x over previous
//
#include <hip/hip_runtime.h>
#include <math.h>

#define S_LEN 512
#define BATCH 64
#define HSZ   512
#define G4    2048

typedef __attribute__((ext_vector_type(8))) short short8;
typedef __attribute__((ext_vector_type(4))) float f32x4;
typedef __attribute__((ext_vector_type(4))) unsigned u32x4;

// ---------------- Static device state ---------------------------------------
__device__ unsigned short g_xbf[(size_t)S_LEN * BATCH * HSZ]; // input as bf16 (32 MB)
__device__ unsigned short g_wbf[G4 * HSZ];                    // W_hh bf16
__device__ unsigned short g_wihbf[G4 * HSZ];                  // W_ih bf16
// h exchange in MFMA A-fragment order: [(kk*64 + quad*16 + m)*8 + e],
// hi/lo bf16 planes (hi+lo ~= fp23), double-buffered, per batch-group.
__device__ unsigned short g_hfhi[2][4][8192];
__device__ unsigned short g_hflo[2][4][8192];
__device__ unsigned g_flags2[4][16];          // monotonic, never reset

__device__ __forceinline__ unsigned short f2bf(float f) {  // RNE fp32->bf16
  unsigned u = __builtin_bit_cast(unsigned, f);
  u += 0x7fffu + ((u >> 16) & 1u);
  return (unsigned short)(u >> 16);
}
__device__ __forceinline__ float bf2f(unsigned short s) {
  return __builtin_bit_cast(float, (unsigned)s << 16);
}
__device__ __forceinline__ float sigmoidf_(float x) { return 1.0f / (1.0f + __expf(-x)); }

// ---------------- Kernel A: input fp32 -> bf16 -------------------------------
__global__ __launch_bounds__(256) void xcvt(const float* __restrict__ x) {
  const size_t i = ((size_t)blockIdx.x * 256 + threadIdx.x) * 8;
  const float4 a = *(const float4*)(x + i);
  const float4 b = *(const float4*)(x + i + 4);
  ushort4 o0, o1;
  o0.x = f2bf(a.x); o0.y = f2bf(a.y); o0.z = f2bf(a.z); o0.w = f2bf(a.w);
  o1.x = f2bf(b.x); o1.y = f2bf(b.y); o1.z = f2bf(b.z); o1.w = f2bf(b.w);
  *(ushort4*)(g_xbf + i) = o0;
  *(ushort4*)(g_xbf + i + 4) = o1;
}

// ---------------- Kernel B: W_hh / W_ih fp32 -> bf16 ------------------------
__global__ __launch_bounds__(256) void wcvt(const float* __restrict__ whh,
                                            const float* __restrict__ wih) {
  const int b = blockIdx.x;
  const float* src = (b < 1024) ? whh : wih;
  unsigned short* dst = (b < 1024) ? g_wbf : g_wihbf;
  const int i = ((b & 1023) * 256 + threadIdx.x) * 4;
  const float4 v = *(const float4*)(src + i);
  ushort4 o;
  o.x = f2bf(v.x); o.y = f2bf(v.y); o.z = f2bf(v.z); o.w = f2bf(v.w);
  *(ushort4*)(dst + i) = o;
}

// ---------------- Kernel C: x_proj = input @ W_ih^T + bias (bf16 MFMA) ------
// 128x128 tile, BK=32, identity-fragment LDS layout (conflict-free).
// Grid 4096 = 256 m-tiles x 16 n-tiles (n inner for x-row L2 reuse).
__global__ __launch_bounds__(256) void xproj_mfma(
    const float* __restrict__ bih,
    const float* __restrict__ bhh,
    float* __restrict__ C)
{
  __shared__ unsigned short Af[4096];   // 8 KB: chunk c=(msub*64+quad*16+mm), 8 shorts
  __shared__ unsigned short Bfs[4096];  // 8 KB: chunk c=(nsub*64+quad*16+nn)
  const int tid = threadIdx.x;
  const int l = tid & 63, w = tid >> 6;
  const int bm = blockIdx.x >> 4, bn = blockIdx.x & 15;
  const int m0 = bm << 7, n0 = bn << 7;

  // Staging decomposition: thread stages chunks c0=tid, c1=tid+256 of A and B
  const int c0 = tid, c1 = tid + 256;
  const int ms0 = c0 >> 6, q0 = (c0 >> 4) & 3, r0 = c0 & 15;
  const int ms1 = c1 >> 6, q1 = (c1 >> 4) & 3, r1 = c1 & 15;
  const size_t aoff0 = (size_t)(m0 + (ms0 << 4) + r0) * 512 + (q0 << 3);
  const size_t aoff1 = (size_t)(m0 + (ms1 << 4) + r1) * 512 + (q1 << 3);
  const size_t boff0 = (size_t)(n0 + (ms0 << 4) + r0) * 512 + (q0 << 3);
  const size_t boff1 = (size_t)(n0 + (ms1 << 4) + r1) * 512 + (q1 << 3);

  f32x4 acc[8][2];
  #pragma unroll
  for (int i = 0; i < 8; ++i) {
    acc[i][0] = (f32x4){0.f, 0.f, 0.f, 0.f};
    acc[i][1] = (f32x4){0.f, 0.f, 0.f, 0.f};
  }

  for (int kb = 0; kb < 512; kb += 32) {
    const uint4 a0 = *(const uint4*)(g_xbf + aoff0 + kb);
    const uint4 a1 = *(const uint4*)(g_xbf + aoff1 + kb);
    const uint4 b0 = *(const uint4*)(g_wihbf + boff0 + kb);
    const uint4 b1 = *(const uint4*)(g_wihbf + boff1 + kb);
    __syncthreads();   // previous iteration's LDS reads complete
    *(uint4*)(Af + c0 * 8) = a0;
    *(uint4*)(Af + c1 * 8) = a1;
    *(uint4*)(Bfs + c0 * 8) = b0;
    *(uint4*)(Bfs + c1 * 8) = b1;
    __syncthreads();
    short8 bfr[2];
    bfr[0] = *(const short8*)(Bfs + ((w * 2 + 0) * 64 + l) * 8);
    bfr[1] = *(const short8*)(Bfs + ((w * 2 + 1) * 64 + l) * 8);
    #pragma unroll
    for (int ms = 0; ms < 8; ++ms) {
      const short8 af = *(const short8*)(Af + (ms * 64 + l) * 8);
      acc[ms][0] = __builtin_amdgcn_mfma_f32_16x16x32_bf16(af, bfr[0], acc[ms][0], 0, 0, 0);
      acc[ms][1] = __builtin_amdgcn_mfma_f32_16x16x32_bf16(af, bfr[1], acc[ms][1], 0, 0, 0);
    }
  }

  const int col = l & 15, quad = l >> 4;
  float bias[2];
  #pragma unroll
  for (int p = 0; p < 2; ++p) {
    const int n = n0 + ((w * 2 + p) << 4) + col;
    bias[p] = bih[n] + bhh[n];
  }
  #pragma unroll
  for (int ms = 0; ms < 8; ++ms)
    #pragma unroll
    for (int p = 0; p < 2; ++p)
      #pragma unroll
      for (int i = 0; i < 4; ++i) {
        const int m = m0 + (ms << 4) + (quad << 2) + i;
        const int n = n0 + ((w * 2 + p) << 4) + col;
        C[(size_t)m * 2048 + n] = acc[ms][p][i] + bias[p];
      }
}

// ---------------- Kernel D: persistent MFMA recurrence ----------------------
// 64 blocks = 4 batch-groups (16 b) x 16 j-tiles (32 j). Wave g = gate g,
// 2 MFMA N-subtiles. W_hh bf16 B-frags in VGPRs. h exchanged in fragment
// order (identity staging, conflict-free LDS). Wave-0-only flag polling.
__global__ __launch_bounds__(256, 1) void lstm_rec(
    const float* __restrict__ xproj,  // (S, B, 2048)
    const float* __restrict__ h0,     // (B, 512) fp32
    const float* __restrict__ c0,     // (B, 512) fp32
    float* __restrict__ out)          // (S,B,512) then h_T then c_T
{
  __shared__ unsigned short his[8192];  // A hi plane, fragment order
  __shared__ unsigned short los[8192];  // A lo plane
  __shared__ float gbuf[4 * 16 * 33];   // [gate][b][j] stride 33

  const int tid  = threadIdx.x;
  const int bg   = blockIdx.x & 3;      // batch group (16 batches)
  const int jt   = blockIdx.x >> 2;     // 0..15 j-tile
  const int b0   = bg << 4;
  const int j0   = jt << 5;             // 0..480
  const int lane = tid & 63;
  const int g    = tid >> 6;            // wave id == gate id
  const int m    = lane & 15;
  const int quad = lane >> 4;

  const unsigned base = __hip_atomic_load(&g_flags2[bg][jt], __ATOMIC_RELAXED,
                                          __HIP_MEMORY_SCOPE_AGENT);

  // Preload B-frags: wave g, subtile nt, K-step kk; B[n=lane&15][k=quad*8+j]
  short8 Bf[2][16];
  #pragma unroll
  for (int nt = 0; nt < 2; ++nt)
    #pragma unroll
    for (int kk = 0; kk < 16; ++kk) {
      const int row = (g << 9) + j0 + (nt << 4) + m;   // W_hh row <= 2047
      Bf[nt][kk] = *(const short8*)(g_wbf + row * 512 + kk * 32 + quad * 8);
    }

  // Epilogue ownership: thread -> (batch eb, j-pair ej, ej+1); c in registers
  const int eb = tid >> 4;
  const int ej = (tid & 15) << 1;
  float creg0 = c0[(size_t)(b0 + eb) * 512 + j0 + ej];
  float creg1 = c0[(size_t)(b0 + eb) * 512 + j0 + ej + 1];

  // Producer publish position (fragment order): kk=jt, quad=ej>>3, m=eb
  const int pub = (jt * 64 + ((ej >> 3) << 4) + eb) * 8 + (ej & 7);

  for (int t = 0; t < S_LEN; ++t) {
    // xproj prefetch (independent of h): 4 gates x float2
    const float* xpp = xproj + ((size_t)t * BATCH + b0 + eb) * G4 + j0 + ej;
    const float2 xpi = *(const float2*)(xpp);
    const float2 xpf = *(const float2*)(xpp + 512);
    const float2 xpg = *(const float2*)(xpp + 1024);
    const float2 xpo = *(const float2*)(xpp + 1536);

    if (t > 0) {
      if (g == 0) {
        const unsigned target = base + (unsigned)t;
        const int fl = lane & 15;
        for (;;) {
          const unsigned f = __hip_atomic_load(&g_flags2[bg][fl], __ATOMIC_RELAXED,
                                               __HIP_MEMORY_SCOPE_AGENT);
          if (__all((int)(f - target) >= 0)) break;
          __builtin_amdgcn_s_sleep(1);
        }
      }
      __syncthreads();  // release all waves to stage
      // Identity staging: global frag plane -> LDS frag plane (coherent loads)
      const unsigned short* hp = &g_hfhi[(t - 1) & 1][bg][tid * 8];
      const unsigned short* lp = &g_hflo[(t - 1) & 1][bg][tid * 8];
      u32x4 h0v, h1v, h2v, h3v, l0v, l1v, l2v, l3v;
      asm volatile(
          "global_load_dwordx4 %0, %8, off sc0 sc1\n\t"
          "global_load_dwordx4 %1, %9, off sc0 sc1\n\t"
          "global_load_dwordx4 %2, %10, off sc0 sc1\n\t"
          "global_load_dwordx4 %3, %11, off sc0 sc1\n\t"
          "global_load_dwordx4 %4, %12, off sc0 sc1\n\t"
          "global_load_dwordx4 %5, %13, off sc0 sc1\n\t"
          "global_load_dwordx4 %6, %14, off sc0 sc1\n\t"
          "global_load_dwordx4 %7, %15, off sc0 sc1\n\t"
          "s_waitcnt vmcnt(0)"
          : "=&v"(h0v), "=&v"(h1v), "=&v"(h2v), "=&v"(h3v),
            "=&v"(l0v), "=&v"(l1v), "=&v"(l2v), "=&v"(l3v)
          : "v"(hp), "v"(hp + 2048), "v"(hp + 4096), "v"(hp + 6144),
            "v"(lp), "v"(lp + 2048), "v"(lp + 4096), "v"(lp + 6144)
          : "memory");
      *(u32x4*)(his + tid * 8)        = h0v;
      *(u32x4*)(his + tid * 8 + 2048) = h1v;
      *(u32x4*)(his + tid * 8 + 4096) = h2v;
      *(u32x4*)(his + tid * 8 + 6144) = h3v;
      *(u32x4*)(los + tid * 8)        = l0v;
      *(u32x4*)(los + tid * 8 + 2048) = l1v;
      *(u32x4*)(los + tid * 8 + 4096) = l2v;
      *(u32x4*)(los + tid * 8 + 6144) = l3v;
    } else {
      // t==0: split h0 fp32 -> hi/lo fragment planes in LDS
      const int sr = tid >> 4;          // batch row 0..15
      const int sc = tid & 15;          // kk chunk 0..15
      const float* hp0 = h0 + (size_t)(b0 + sr) * 512 + sc * 32;
      #pragma unroll
      for (int q = 0; q < 4; ++q) {
        const float4 v0 = *(const float4*)(hp0 + q * 8);
        const float4 v1 = *(const float4*)(hp0 + q * 8 + 4);
        ushort4 h4a, l4a, h4b, l4b;
        h4a.x = f2bf(v0.x); l4a.x = f2bf(v0.x - bf2f(h4a.x));
        h4a.y = f2bf(v0.y); l4a.y = f2bf(v0.y - bf2f(h4a.y));
        h4a.z = f2bf(v0.z); l4a.z = f2bf(v0.z - bf2f(h4a.z));
        h4a.w = f2bf(v0.w); l4a.w = f2bf(v0.w - bf2f(h4a.w));
        h4b.x = f2bf(v1.x); l4b.x = f2bf(v1.x - bf2f(h4b.x));
        h4b.y = f2bf(v1.y); l4b.y = f2bf(v1.y - bf2f(h4b.y));
        h4b.z = f2bf(v1.z); l4b.z = f2bf(v1.z - bf2f(h4b.z));
        h4b.w = f2bf(v1.w); l4b.w = f2bf(v1.w - bf2f(h4b.w));
        const int dst = (sc * 64 + q * 16 + sr) * 8;
        *(ushort4*)(his + dst)     = h4a;
        *(ushort4*)(his + dst + 4) = h4b;
        *(ushort4*)(los + dst)     = l4a;
        *(ushort4*)(los + dst + 4) = l4b;
      }
    }
    __syncthreads();

    // MFMA: acc[nt] over K=512 (16 steps), A = hi + lo; wave-contiguous reads
    f32x4 acc0 = {0.f, 0.f, 0.f, 0.f};
    f32x4 acc1 = {0.f, 0.f, 0.f, 0.f};
    const unsigned short* ab = his + lane * 8;
    const unsigned short* lb = los + lane * 8;
    #pragma unroll
    for (int kk = 0; kk < 16; ++kk) {
      const short8 ah = *(const short8*)(ab + kk * 512);
      const short8 al = *(const short8*)(lb + kk * 512);
      acc0 = __builtin_amdgcn_mfma_f32_16x16x32_bf16(ah, Bf[0][kk], acc0, 0, 0, 0);
      acc1 = __builtin_amdgcn_mfma_f32_16x16x32_bf16(ah, Bf[1][kk], acc1, 0, 0, 0);
      acc0 = __builtin_amdgcn_mfma_f32_16x16x32_bf16(al, Bf[0][kk], acc0, 0, 0, 0);
      acc1 = __builtin_amdgcn_mfma_f32_16x16x32_bf16(al, Bf[1][kk], acc1, 0, 0, 0);
    }
    // C layout: col = lane&15 (j), row = quad*4+i (batch)
    #pragma unroll
    for (int i = 0; i < 4; ++i) {
      gbuf[g * 528 + (quad * 4 + i) * 33 + m]      = acc0[i];
      gbuf[g * 528 + (quad * 4 + i) * 33 + 16 + m] = acc1[i];
    }
    __syncthreads();

    // Epilogue: 2 cells per thread
    const float gi0 = gbuf[0 * 528 + eb * 33 + ej]     + xpi.x;
    const float gi1 = gbuf[0 * 528 + eb * 33 + ej + 1] + xpi.y;
    const float gf0 = gbuf[1 * 528 + eb * 33 + ej]     + xpf.x;
    const float gf1 = gbuf[1 * 528 + eb * 33 + ej + 1] + xpf.y;
    const float gg0 = gbuf[2 * 528 + eb * 33 + ej]     + xpg.x;
    const float gg1 = gbuf[2 * 528 + eb * 33 + ej + 1] + xpg.y;
    const float go0 = gbuf[3 * 528 + eb * 33 + ej]     + xpo.x;
    const float go1 = gbuf[3 * 528 + eb * 33 + ej + 1] + xpo.y;

    creg0 = sigmoidf_(gf0) * creg0 + sigmoidf_(gi0) * tanhf(gg0);
    creg1 = sigmoidf_(gf1) * creg1 + sigmoidf_(gi1) * tanhf(gg1);
    const float h0n = sigmoidf_(go0) * tanhf(creg0);
    const float h1n = sigmoidf_(go1) * tanhf(creg1);

    float2 hv; hv.x = h0n; hv.y = h1n;
    *(float2*)(out + ((size_t)t * BATCH + b0 + eb) * HSZ + j0 + ej) = hv;

    if (t < S_LEN - 1) {
      // Publish hi/lo fragment words for step t, then flag
      const unsigned short hh0 = f2bf(h0n), hh1 = f2bf(h1n);
      const unsigned short ll0 = f2bf(h0n - bf2f(hh0)), ll1 = f2bf(h1n - bf2f(hh1));
      const unsigned hpack = (unsigned)hh0 | ((unsigned)hh1 << 16);
      const unsigned lpack = (unsigned)ll0 | ((unsigned)ll1 << 16);
      unsigned* hd = (unsigned*)&g_hfhi[t & 1][bg][pub];
      unsigned* ld = (unsigned*)&g_hflo[t & 1][bg][pub];
      asm volatile(
          "global_store_dword %0, %2, off sc0 sc1\n\t"
          "global_store_dword %1, %3, off sc0 sc1"
          :: "v"(hd), "v"(ld), "v"(hpack), "v"(lpack)
          : "memory");
      asm volatile("s_waitcnt vmcnt(0)" ::: "memory");  // drain own stores
      __syncthreads();
      if (tid == 0) {
        __hip_atomic_store(&g_flags2[bg][jt], base + (unsigned)t + 1u,
                           __ATOMIC_RELAXED, __HIP_MEMORY_SCOPE_AGENT);
      }
    } else {
      // h_T, c_T
      *(float2*)(out + (size_t)S_LEN * BATCH * HSZ + (size_t)(b0 + eb) * HSZ + j0 + ej) = hv;
      float2 cv; cv.x = creg0; cv.y = creg1;
      *(float2*)(out + (size_t)S_LEN * BATCH * HSZ + BATCH * HSZ
                 + (size_t)(b0 + eb) * HSZ + j0 + ej) = cv;
    }
  }
}

extern "C" void kernel_launch(void* const* d_in, const int* in_sizes, int n_in,
                              void* d_out, int out_size, void* d_ws, size_t ws_size,
                              hipStream_t stream) {
  (void)in_sizes; (void)n_in; (void)out_size; (void)ws_size;
  const float* input = (const float*)d_in[0];  // (512, 64, 512)
  const float* h0p   = (const float*)d_in[1];  // (64, 512)
  const float* c0p   = (const float*)d_in[2];  // (64, 512)
  const float* wih   = (const float*)d_in[3];  // (1, 2048, 512)
  const float* whhp  = (const float*)d_in[4];  // (1, 2048, 512)
  const float* bih   = (const float*)d_in[5];  // (1, 2048)
  const float* bhh   = (const float*)d_in[6];  // (1, 2048)
  float* outp  = (float*)d_out;
  float* xproj = (float*)d_ws;                 // 256 MB

  xcvt<<<dim3(8192), dim3(256), 0, stream>>>(input);
  wcvt<<<dim3(2048), dim3(256), 0, stream>>>(whhp, wih);
  xproj_mfma<<<dim3(4096), dim3(256), 0, stream>>>(bih, bhh, xproj);

  const float* xp = xproj;
  void* args[] = { (void*)&xp, (void*)&h0p, (void*)&c0p, (void*)&outp };
  hipLaunchCooperativeKernel((const void*)lstm_rec, dim3(64), dim3(256),
                             args, 0, stream);
}